// Round 2
// baseline (301.412 us; speedup 1.0000x reference)
//
#include <hip/hip_runtime.h>
#include <hip/hip_bf16.h>
#include <stdint.h>

// ---------------------------------------------------------------------------
// Causal MHA, B=2 T=4096 D=768 H=12 dk=64, bf16 MFMA path.
// R9: flash_attn is LATENCY-bound (R8 post-mortem: halving LDS traffic made
// it slower; both pipes <40%). Keep 32-row wide waves (2x ILP, 0.5x LDS
// traffic) but restore 4-wave blocks: 128-row q tile, 768 blocks (3/CU all
// resident, 12 waves/CU). Heavy+light pairing for per-CU load balance.
// ---------------------------------------------------------------------------

typedef __attribute__((ext_vector_type(8))) short bf16x8;   // 8 bf16 = 4 VGPRs
typedef __attribute__((ext_vector_type(4))) short bf16x4;   // 4 bf16 = 2 VGPRs
typedef __attribute__((ext_vector_type(4))) float f32x4;

#define TT 4096
#define NH 12
#define DK 64
#define DMODEL 768
#define NQKV 2304

__device__ __forceinline__ unsigned short f2bf(float f) {
    union { float f; unsigned u; } v; v.f = f;
    unsigned u = v.u;
    return (unsigned short)((u + 0x7fffu + ((u >> 16) & 1u)) >> 16);  // RNE
}
__device__ __forceinline__ unsigned fbits(float f) {
    union { float f; unsigned u; } v; v.f = f; return v.u;
}
// pack two fp32 -> two bf16 (round-half-up): lo16=a, hi16=b
__device__ __forceinline__ unsigned pack_bf2(float a, float b) {
    return __builtin_amdgcn_perm(fbits(b) + 0x8000u, fbits(a) + 0x8000u, 0x07060302u);
}
// async global->LDS, 16B/lane; LDS dest = wave-uniform base + lane*16
__device__ __forceinline__ void glds16(const void* g, void* l) {
    __builtin_amdgcn_global_load_lds(
        (const __attribute__((address_space(1))) void*)g,
        (__attribute__((address_space(3))) void*)l, 16, 0, 0);
}

// ---------------------------------------------------------------------------
// prep: x->bf16 (blocks [0,6144)), W_qkv transpose ([6144,6576)),
// W_out transpose ([6576,6720)).
// ---------------------------------------------------------------------------
__global__ __launch_bounds__(256)
void prep(const float* __restrict__ x, unsigned short* __restrict__ xb,
          const float* __restrict__ Wq, unsigned short* __restrict__ Wqt,
          const float* __restrict__ Wo, unsigned short* __restrict__ Wot) {
    int b = blockIdx.x;
    if (b < 6144) {
        int i = (b * 256 + threadIdx.x) * 4;
        float4 v = *(const float4*)(x + i);
        uint2 u;
        u.x = pack_bf2(v.x, v.y);
        u.y = pack_bf2(v.z, v.w);
        *(uint2*)(xb + i) = u;
        return;
    }
    __shared__ unsigned short tile[64][65];
    const float* W; unsigned short* Wt; int K, N, bx, by;
    if (b < 6144 + 432) {
        int bb = b - 6144; bx = bb % 36; by = bb / 36;
        W = Wq; Wt = Wqt; K = DMODEL; N = NQKV;
    } else {
        int bb = b - 6576; bx = bb % 12; by = bb / 12;
        W = Wo; Wt = Wot; K = DMODEL; N = DMODEL;
    }
    int k0 = by * 64, n0 = bx * 64;
    int c = threadIdx.x & 63;
    int r0 = threadIdx.x >> 6;
    for (int p = 0; p < 16; ++p) {
        int r = r0 + p * 4;
        tile[r][c] = f2bf(W[(size_t)(k0 + r) * N + n0 + c]);
    }
    __syncthreads();
    for (int p = 0; p < 16; ++p) {
        int n = r0 + p * 4;
        Wt[(size_t)(n0 + n) * K + k0 + c] = tile[c][n];
    }
}

// ---------------------------------------------------------------------------
// QKV GEMM computing C^T: tile rows = qkv-cols (A = Wqkv_t), cols = tokens
// (B = x_bf). Q (incl. bias) pre-scaled by log2(e)/8.
// launch_bounds(256,3): 3 blocks/CU (m97 operating point).
// ---------------------------------------------------------------------------
__global__ __launch_bounds__(256, 3)
void gemm_qkv(const unsigned short* __restrict__ Amat, const unsigned short* __restrict__ Bmat,
              const float* __restrict__ bias, unsigned short* __restrict__ qb,
              unsigned short* __restrict__ kb, unsigned short* __restrict__ vtb) {
    __shared__ unsigned short As[128 * 64];
    __shared__ unsigned short Bs[128 * 64];
    const int K = DMODEL;
    int m0 = blockIdx.y * 128, n0 = blockIdx.x * 128;   // m: qkv-col, n: token
    int tid = threadIdx.x, lane = tid & 63, w = tid >> 6;
    int wm = (w >> 1) * 64, wn = (w & 1) * 64;
    int quad = lane >> 4, lc = lane & 15;

    const unsigned short* agp[4]; const unsigned short* bgp[4];
    unsigned short* alp[4]; unsigned short* blp[4];
    for (int p = 0; p < 4; ++p) {
        int c = (w * 4 + p) * 64 + lane;      // 16B chunk id in tile
        int row = c >> 3, pc = c & 7;
        int gc = pc ^ (row & 7);              // swizzle inverse
        agp[p] = Amat + (size_t)(m0 + row) * K + gc * 8;
        bgp[p] = Bmat + (size_t)(n0 + row) * K + gc * 8;
        alp[p] = &As[(w * 4 + p) * 512];
        blp[p] = &Bs[(w * 4 + p) * 512];
    }
    int foff[4][2];
    for (int mt = 0; mt < 4; ++mt)
        for (int h = 0; h < 2; ++h)
            foff[mt][h] = (mt * 16 + lc) * 64 + (((quad + 4 * h) ^ (lc & 7)) * 8);

    f32x4 acc[4][4];
    for (int a = 0; a < 4; ++a)
        for (int b2 = 0; b2 < 4; ++b2) acc[a][b2] = (f32x4){0.f, 0.f, 0.f, 0.f};

    for (int k0 = 0; k0 < K; k0 += 64) {
        for (int p = 0; p < 4; ++p) {
            glds16(agp[p] + k0, alp[p]);
            glds16(bgp[p] + k0, blp[p]);
        }
        __syncthreads();
        bf16x8 af[4][2], bfr[4][2];
        for (int mt = 0; mt < 4; ++mt)
            for (int h = 0; h < 2; ++h) {
                af[mt][h]  = *(const bf16x8*)(&As[wm * 64 + foff[mt][h]]);
                bfr[mt][h] = *(const bf16x8*)(&Bs[wn * 64 + foff[mt][h]]);
            }
        for (int mt = 0; mt < 4; ++mt)
            for (int nt = 0; nt < 4; ++nt) {
                acc[mt][nt] = __builtin_amdgcn_mfma_f32_16x16x32_bf16(
                    af[mt][0], bfr[nt][0], acc[mt][nt], 0, 0, 0);
                acc[mt][nt] = __builtin_amdgcn_mfma_f32_16x16x32_bf16(
                    af[mt][1], bfr[nt][1], acc[mt][nt], 0, 0, 0);
            }
        __syncthreads();
    }
    const float c2q = 0.18033688f;            // log2(e)/8 folded into Q
    for (int mt = 0; mt < 4; ++mt) {
        int colv = m0 + wm + mt * 16 + quad * 4;      // 4 consecutive qkv-cols
        float4 bv = *(const float4*)(bias + colv);
        int h = colv / 192;
        int r = colv - h * 192;
        int which = r >> 6;                            // uniform over i (64-aligned)
        int d0 = r & 63;
        for (int nt = 0; nt < 4; ++nt) {
            int tok = n0 + wn + nt * 16 + lc;
            int b = tok >> 12, t = tok & 4095;
            size_t bh = (size_t)(b * NH + h);
            float v0 = acc[mt][nt][0] + bv.x, v1 = acc[mt][nt][1] + bv.y;
            float v2 = acc[mt][nt][2] + bv.z, v3 = acc[mt][nt][3] + bv.w;
            if (which == 0) {
                uint2 u;
                u.x = pack_bf2(v0 * c2q, v1 * c2q);
                u.y = pack_bf2(v2 * c2q, v3 * c2q);
                *(uint2*)(qb + (bh * TT + t) * DK + d0) = u;
            } else if (which == 1) {
                uint2 u;
                u.x = pack_bf2(v0, v1);
                u.y = pack_bf2(v2, v3);
                *(uint2*)(kb + (bh * TT + t) * DK + d0) = u;
            } else {
                unsigned short* vp = vtb + (bh * DK + d0) * TT + t;
                vp[0] = f2bf(v0); vp[TT] = f2bf(v1);
                vp[2 * TT] = f2bf(v2); vp[3 * TT] = f2bf(v3);
            }
        }
    }
}

// ---------------------------------------------------------------------------
// Flash attention tile body, wide-wave: each wave owns 32 q rows as two
// 16-col fragments f=0,1. K fragments (kf0,kf1) and V fragments (vf) are
// read from LDS ONCE and feed both q-fragments. The two fragments give two
// independent MFMA/exp chains for latency hiding. Row-sum l via ones x P.
// ---------------------------------------------------------------------------
template <bool DIAG>
__device__ __forceinline__ void flash_tile(const unsigned short* __restrict__ Kb,
                                           const unsigned short* __restrict__ Vb,
                                           const bf16x8 (&qf)[2][2],
                                           f32x4 (&o)[2][4], f32x4 (&ol)[2],
                                           int kt, int q0, int quad, int lc) {
    int c0 = quad ^ (lc & 7);
    int sw = lc & 7;
    const bf16x4 ones = {(short)0x3F80, (short)0x3F80, (short)0x3F80, (short)0x3F80};
    for (int ktile = 0; ktile < 4; ++ktile) {
        bf16x8 kf0 = *(const bf16x8*)(&Kb[(ktile * 16 + lc) * 64 + c0 * 8]);
        bf16x8 kf1 = *(const bf16x8*)(&Kb[(ktile * 16 + lc) * 64 + (c0 ^ 4) * 8]);
        bf16x4 pcv[2];
        for (int f = 0; f < 2; ++f) {
            f32x4 s = (f32x4){0.f, 0.f, 0.f, 0.f};
            s = __builtin_amdgcn_mfma_f32_16x16x32_bf16(kf0, qf[f][0], s, 0, 0, 0);
            s = __builtin_amdgcn_mfma_f32_16x16x32_bf16(kf1, qf[f][1], s, 0, 0, 0);
            float p[4];
            if (DIAG) {
                int key0 = kt + ktile * 16 + quad * 4;
                int qcol = q0 + f * 16 + lc;
                for (int i = 0; i < 4; ++i) {
                    float e = __builtin_amdgcn_exp2f(s[i]);
                    if (key0 + i > qcol) e = 0.f;
                    p[i] = e;
                }
            } else {
                for (int i = 0; i < 4; ++i) p[i] = __builtin_amdgcn_exp2f(s[i]);
            }
            union { uint2 u; bf16x4 v; } pc;
            pc.u.x = pack_bf2(p[0], p[1]);
            pc.u.y = pack_bf2(p[2], p[3]);
            pcv[f] = pc.v;
            ol[f] = __builtin_amdgcn_mfma_f32_16x16x16bf16_1k(ones, pcv[f], ol[f], 0, 0, 0);
        }
        int c8 = (ktile * 2 + (quad >> 1)) ^ sw;
        int voff = c8 * 8 + (quad & 1) * 4;
        for (int dt = 0; dt < 4; ++dt) {
            bf16x4 vf = *(const bf16x4*)(&Vb[(dt * 16 + lc) * 64 + voff]);
            o[0][dt] = __builtin_amdgcn_mfma_f32_16x16x16bf16_1k(vf, pcv[0], o[0][dt], 0, 0, 0);
            o[1][dt] = __builtin_amdgcn_mfma_f32_16x16x16bf16_1k(vf, pcv[1], o[1][dt], 0, 0, 0);
        }
    }
}

// ---------------------------------------------------------------------------
// Flash attention (causal). 256 thr = 4 waves x 32 q rows (128-row q tile);
// 768 blocks total (3/CU, all co-resident, 12 waves/CU). Heavy+light q-block
// pairing in dispatch order for per-CU balance. K/V glds double-buffer
// (waves 0-1 stage K, waves 2-3 stage V); P in registers; fixed-max softmax.
// Per-wave tile classes: full / diagonal / fully-masked (skip compute).
// ---------------------------------------------------------------------------
__global__ __launch_bounds__(256)
void flash_attn(const unsigned short* __restrict__ qbuf,
                const unsigned short* __restrict__ kbuf,
                const unsigned short* __restrict__ vtbuf,
                unsigned short* __restrict__ ctx) {
    __shared__ unsigned short Ks[2][64 * 64];      // [key][d], swizzled
    __shared__ unsigned short Vs[2][64 * 64];      // [d][key], swizzled
    int bh = blockIdx.x;
    int yy = (int)blockIdx.y;                      // 0..31
    // pair heavy+light: y=0 -> qblk 31 (64 tiles), y=1 -> qblk 0 (2 tiles), ...
    int qblk = (yy & 1) ? (yy >> 1) : (31 - (yy >> 1));
    int tid = threadIdx.x, lane = tid & 63, w = tid >> 6;
    int quad = lane >> 4, lc = lane & 15;
    const size_t base = (size_t)bh * TT * DK;
    const unsigned short* kb = kbuf + base;
    const unsigned short* vb = vtbuf + base;
    int col8 = ((lane & 7) ^ (lane >> 3)) * 8;     // glds swizzled source col
    int klane = (lane >> 3) * DK + col8;
    int vlane = (lane >> 3) * TT + col8;
    size_t hb = (size_t)(bh / NH) * TT * DMODEL + (size_t)(bh % NH) * DK;

    int q0 = qblk * 128 + w * 32;                  // this wave's 32 q rows
    int ntile = 2 * qblk + 2;

    bf16x8 qf[2][2];                               // pre-scaled Q fragments
    for (int f = 0; f < 2; ++f) {
        const unsigned short* qp = qbuf + base + (size_t)(q0 + f * 16 + lc) * DK;
        qf[f][0] = *(const bf16x8*)(qp + quad * 8);
        qf[f][1] = *(const bf16x8*)(qp + 32 + quad * 8);
    }
    f32x4 o[2][4];
    for (int f = 0; f < 2; ++f)
        for (int dt = 0; dt < 4; ++dt) o[f][dt] = (f32x4){0.f, 0.f, 0.f, 0.f};
    f32x4 ol[2];
    ol[0] = (f32x4){0.f, 0.f, 0.f, 0.f};
    ol[1] = (f32x4){0.f, 0.f, 0.f, 0.f};

    {   // stage tile 0 -> buf 0 (waves 0-1: K rows, waves 2-3: Vt rows)
        int rb = (w & 1) * 4;
        if (w < 2)
            for (int r = 0; r < 4; ++r)
                glds16(kb + (size_t)((rb + r) * 8) * DK + klane, &Ks[0][(rb + r) * 512]);
        else
            for (int r = 0; r < 4; ++r)
                glds16(vb + (size_t)((rb + r) * 8) * TT + vlane, &Vs[0][(rb + r) * 512]);
    }
    __syncthreads();

    for (int ti = 0; ti < ntile; ++ti) {
        int cur = ti & 1;
        if (ti + 1 < ntile) {                      // async prefetch -> alt buf
            int kn = (ti + 1) * 64;
            int rb = (w & 1) * 4;
            if (w < 2)
                for (int r = 0; r < 4; ++r)
                    glds16(kb + (size_t)(kn + (rb + r) * 8) * DK + klane,
                           &Ks[cur ^ 1][(rb + r) * 512]);
            else
                for (int r = 0; r < 4; ++r)
                    glds16(vb + (size_t)((rb + r) * 8) * TT + kn + vlane,
                           &Vs[cur ^ 1][(rb + r) * 512]);
        }
        int kt = ti * 64;
        if (kt <= q0 + 31) {                       // not fully masked (wave-uniform)
            if (kt + 63 > q0)
                flash_tile<true>(&Ks[cur][0], &Vs[cur][0], qf, o, ol,
                                 kt, q0, quad, lc);
            else
                flash_tile<false>(&Ks[cur][0], &Vs[cur][0], qf, o, ol,
                                  kt, q0, quad, lc);
        }
        __syncthreads();                           // cur consumed; alt staged
    }

    // epilogue: l_q already complete per lane (ones-MFMA); normalize, store
    for (int f = 0; f < 2; ++f) {
        float inv = 1.f / ol[f][0];
        int t = q0 + f * 16 + lc;
        unsigned short* cp = ctx + hb + (size_t)t * DMODEL;
        for (int dt = 0; dt < 4; ++dt) {
            uint2 u;
            u.x = pack_bf2(o[f][dt][0] * inv, o[f][dt][1] * inv);
            u.y = pack_bf2(o[f][dt][2] * inv, o[f][dt][3] * inv);
            *(uint2*)(cp + dt * 16 + quad * 4) = u;
        }
    }
}

// ---------------------------------------------------------------------------
// Out GEMM computing C^T, 64 out-cols x 128 tokens per block (768 blocks).
// A = Wout_t (64 rows), B = ctx (128 rows); unified LDS, glds staging.
// launch_bounds(256,4): 4 blocks/CU.
// ---------------------------------------------------------------------------
__global__ __launch_bounds__(256, 4)
void gemm_out(const unsigned short* __restrict__ Amat, const unsigned short* __restrict__ Bmat,
              const float* __restrict__ bias, float* __restrict__ out) {
    __shared__ unsigned short S[(64 + 128) * 64];   // A then B, 24 KB
    const int K = DMODEL;
    int m0 = blockIdx.y * 64, n0 = blockIdx.x * 128;   // m: out-col, n: token
    int tid = threadIdx.x, lane = tid & 63, w = tid >> 6;
    int wm = (w & 1) * 32, wn = (w >> 1) * 64;
    int quad = lane >> 4, lc = lane & 15;

    const unsigned short* gp[6]; unsigned short* lp[6];
    for (int p = 0; p < 6; ++p) {
        int c = (w * 6 + p) * 64 + lane;      // 16B chunk id (A:0..511, B:512..1535)
        if (c < 512) {
            int row = c >> 3, gc = (c & 7) ^ (row & 7);
            gp[p] = Amat + (size_t)(m0 + row) * K + gc * 8;
        } else {
            int cb = c - 512;
            int row = cb >> 3, gc = (cb & 7) ^ (row & 7);
            gp[p] = Bmat + (size_t)(n0 + row) * K + gc * 8;
        }
        lp[p] = &S[(w * 6 + p) * 512];
    }
    int foffA[2][2], foffB[4][2];
    for (int mt = 0; mt < 2; ++mt)
        for (int h = 0; h < 2; ++h)
            foffA[mt][h] = (wm + mt * 16 + lc) * 64 + (((quad + 4 * h) ^ (lc & 7)) * 8);
    for (int nt = 0; nt < 4; ++nt)
        for (int h = 0; h < 2; ++h)
            foffB[nt][h] = 4096 + (wn + nt * 16 + lc) * 64 + (((quad + 4 * h) ^ (lc & 7)) * 8);

    f32x4 acc[2][4];
    for (int a = 0; a < 2; ++a)
        for (int b2 = 0; b2 < 4; ++b2) acc[a][b2] = (f32x4){0.f, 0.f, 0.f, 0.f};

    for (int k0 = 0; k0 < K; k0 += 64) {
        for (int p = 0; p < 6; ++p) glds16(gp[p] + k0, lp[p]);
        __syncthreads();
        bf16x8 af[2][2], bfr[4][2];
        for (int mt = 0; mt < 2; ++mt)
            for (int h = 0; h < 2; ++h) af[mt][h] = *(const bf16x8*)(&S[foffA[mt][h]]);
        for (int nt = 0; nt < 4; ++nt)
            for (int h = 0; h < 2; ++h) bfr[nt][h] = *(const bf16x8*)(&S[foffB[nt][h]]);
        for (int mt = 0; mt < 2; ++mt)
            for (int nt = 0; nt < 4; ++nt) {
                acc[mt][nt] = __builtin_amdgcn_mfma_f32_16x16x32_bf16(
                    af[mt][0], bfr[nt][0], acc[mt][nt], 0, 0, 0);
                acc[mt][nt] = __builtin_amdgcn_mfma_f32_16x16x32_bf16(
                    af[mt][1], bfr[nt][1], acc[mt][nt], 0, 0, 0);
            }
        __syncthreads();
    }
    for (int mt = 0; mt < 2; ++mt) {
        int colv = m0 + wm + mt * 16 + quad * 4;
        float4 bv = *(const float4*)(bias + colv);
        for (int nt = 0; nt < 4; ++nt) {
            int tok = n0 + wn + nt * 16 + lc;
            float4 ov;
            ov.x = acc[mt][nt][0] + bv.x;
            ov.y = acc[mt][nt][1] + bv.y;
            ov.z = acc[mt][nt][2] + bv.z;
            ov.w = acc[mt][nt][3] + bv.w;
            *(float4*)(out + (size_t)tok * DMODEL + colv) = ov;
        }
    }
}

// ---------------------------------------------------------------------------
extern "C" void kernel_launch(void* const* d_in, const int* in_sizes, int n_in,
                              void* d_out, int out_size, void* d_ws, size_t ws_size,
                              hipStream_t stream) {
    const float* x     = (const float*)d_in[0];
    // d_in[1] = mask (hard-coded causal; unused)
    const float* W_qkv = (const float*)d_in[2];
    const float* b_qkv = (const float*)d_in[3];
    const float* W_out = (const float*)d_in[4];
    const float* b_out = (const float*)d_in[5];
    float* out = (float*)d_out;

    unsigned short* ws = (unsigned short*)d_ws;
    unsigned short* Wqkv_t = ws;                                    // 2304*768
    unsigned short* Wout_t = Wqkv_t + (size_t)NQKV * DMODEL;        // 768*768
    unsigned short* q_buf  = Wout_t + (size_t)DMODEL * DMODEL;      // 24*4096*64
    unsigned short* k_buf  = q_buf  + (size_t)2 * NH * TT * DK;
    unsigned short* vt_buf = k_buf  + (size_t)2 * NH * TT * DK;
    unsigned short* ctx    = vt_buf + (size_t)2 * NH * TT * DK;     // 2*4096*768
    unsigned short* x_bf   = ctx;   // alias: dead before flash writes ctx

    prep<<<dim3(6720), 256, 0, stream>>>(x, x_bf, W_qkv, Wqkv_t, W_out, Wout_t);
    gemm_qkv<<<dim3((2 * TT) / 128, NQKV / 128), 256, 0, stream>>>(
        Wqkv_t, x_bf, b_qkv, q_buf, k_buf, vt_buf);
    flash_attn<<<dim3(2 * NH, 32), 256, 0, stream>>>(q_buf, k_buf, vt_buf, ctx);
    gemm_out<<<dim3((2 * TT) / 128, DMODEL / 64), 256, 0, stream>>>(
        Wout_t, ctx, b_out, out);
}

// Round 4
// 278.904 us; speedup vs baseline: 1.0807x; 1.0807x over previous
//
#include <hip/hip_runtime.h>
#include <hip/hip_bf16.h>
#include <stdint.h>

// ---------------------------------------------------------------------------
// Causal MHA, B=2 T=4096 D=768 H=12 dk=64, bf16 MFMA path.
// R11 = R10 with compile fix: no local pointer arrays initialized from
// __shared__ (gfx950 rejects addrspacecast in static initializers) —
// buffer pointers computed by byte arithmetic at use-time instead.
// R10 design: R7 schedule (1536 small blocks, 4 waves, heavy-first) kept
// exactly, but keys (not q) split across waves: wave w owns ktile w of every
// 64-key tile, all 64 q rows. K/V LDS reads drop 4x (80KB->32KB/block-tile),
// per-wave ILP rises to 4 independent QK->exp->PV chains. Partial o/l are
// summed across waves once per block via LDS (aliased over dead K/V bufs).
// Fixed-max softmax => partials combine by pure addition.
// ---------------------------------------------------------------------------

typedef __attribute__((ext_vector_type(8))) short bf16x8;   // 8 bf16 = 4 VGPRs
typedef __attribute__((ext_vector_type(4))) short bf16x4;   // 4 bf16 = 2 VGPRs
typedef __attribute__((ext_vector_type(4))) float f32x4;

#define TT 4096
#define NH 12
#define DK 64
#define DMODEL 768
#define NQKV 2304

__device__ __forceinline__ unsigned short f2bf(float f) {
    union { float f; unsigned u; } v; v.f = f;
    unsigned u = v.u;
    return (unsigned short)((u + 0x7fffu + ((u >> 16) & 1u)) >> 16);  // RNE
}
__device__ __forceinline__ unsigned fbits(float f) {
    union { float f; unsigned u; } v; v.f = f; return v.u;
}
// pack two fp32 -> two bf16 (round-half-up): lo16=a, hi16=b
__device__ __forceinline__ unsigned pack_bf2(float a, float b) {
    return __builtin_amdgcn_perm(fbits(b) + 0x8000u, fbits(a) + 0x8000u, 0x07060302u);
}
// async global->LDS, 16B/lane; LDS dest = wave-uniform base + lane*16
__device__ __forceinline__ void glds16(const void* g, void* l) {
    __builtin_amdgcn_global_load_lds(
        (const __attribute__((address_space(1))) void*)g,
        (__attribute__((address_space(3))) void*)l, 16, 0, 0);
}

// ---------------------------------------------------------------------------
// prep: x->bf16 (blocks [0,6144)), W_qkv transpose ([6144,6576)),
// W_out transpose ([6576,6720)).
// ---------------------------------------------------------------------------
__global__ __launch_bounds__(256)
void prep(const float* __restrict__ x, unsigned short* __restrict__ xb,
          const float* __restrict__ Wq, unsigned short* __restrict__ Wqt,
          const float* __restrict__ Wo, unsigned short* __restrict__ Wot) {
    int b = blockIdx.x;
    if (b < 6144) {
        int i = (b * 256 + threadIdx.x) * 4;
        float4 v = *(const float4*)(x + i);
        uint2 u;
        u.x = pack_bf2(v.x, v.y);
        u.y = pack_bf2(v.z, v.w);
        *(uint2*)(xb + i) = u;
        return;
    }
    __shared__ unsigned short tile[64][65];
    const float* W; unsigned short* Wt; int K, N, bx, by;
    if (b < 6144 + 432) {
        int bb = b - 6144; bx = bb % 36; by = bb / 36;
        W = Wq; Wt = Wqt; K = DMODEL; N = NQKV;
    } else {
        int bb = b - 6576; bx = bb % 12; by = bb / 12;
        W = Wo; Wt = Wot; K = DMODEL; N = DMODEL;
    }
    int k0 = by * 64, n0 = bx * 64;
    int c = threadIdx.x & 63;
    int r0 = threadIdx.x >> 6;
    for (int p = 0; p < 16; ++p) {
        int r = r0 + p * 4;
        tile[r][c] = f2bf(W[(size_t)(k0 + r) * N + n0 + c]);
    }
    __syncthreads();
    for (int p = 0; p < 16; ++p) {
        int n = r0 + p * 4;
        Wt[(size_t)(n0 + n) * K + k0 + c] = tile[c][n];
    }
}

// ---------------------------------------------------------------------------
// QKV GEMM computing C^T: tile rows = qkv-cols (A = Wqkv_t), cols = tokens
// (B = x_bf). Q (incl. bias) pre-scaled by log2(e)/8.
// launch_bounds(256,3): 3 blocks/CU (m97 operating point).
// ---------------------------------------------------------------------------
__global__ __launch_bounds__(256, 3)
void gemm_qkv(const unsigned short* __restrict__ Amat, const unsigned short* __restrict__ Bmat,
              const float* __restrict__ bias, unsigned short* __restrict__ qb,
              unsigned short* __restrict__ kb, unsigned short* __restrict__ vtb) {
    __shared__ unsigned short As[128 * 64];
    __shared__ unsigned short Bs[128 * 64];
    const int K = DMODEL;
    int m0 = blockIdx.y * 128, n0 = blockIdx.x * 128;   // m: qkv-col, n: token
    int tid = threadIdx.x, lane = tid & 63, w = tid >> 6;
    int wm = (w >> 1) * 64, wn = (w & 1) * 64;
    int quad = lane >> 4, lc = lane & 15;

    const unsigned short* agp[4]; const unsigned short* bgp[4];
    unsigned short* alp[4]; unsigned short* blp[4];
    for (int p = 0; p < 4; ++p) {
        int c = (w * 4 + p) * 64 + lane;      // 16B chunk id in tile
        int row = c >> 3, pc = c & 7;
        int gc = pc ^ (row & 7);              // swizzle inverse
        agp[p] = Amat + (size_t)(m0 + row) * K + gc * 8;
        bgp[p] = Bmat + (size_t)(n0 + row) * K + gc * 8;
        alp[p] = &As[(w * 4 + p) * 512];
        blp[p] = &Bs[(w * 4 + p) * 512];
    }
    int foff[4][2];
    for (int mt = 0; mt < 4; ++mt)
        for (int h = 0; h < 2; ++h)
            foff[mt][h] = (mt * 16 + lc) * 64 + (((quad + 4 * h) ^ (lc & 7)) * 8);

    f32x4 acc[4][4];
    for (int a = 0; a < 4; ++a)
        for (int b2 = 0; b2 < 4; ++b2) acc[a][b2] = (f32x4){0.f, 0.f, 0.f, 0.f};

    for (int k0 = 0; k0 < K; k0 += 64) {
        for (int p = 0; p < 4; ++p) {
            glds16(agp[p] + k0, alp[p]);
            glds16(bgp[p] + k0, blp[p]);
        }
        __syncthreads();
        bf16x8 af[4][2], bfr[4][2];
        for (int mt = 0; mt < 4; ++mt)
            for (int h = 0; h < 2; ++h) {
                af[mt][h]  = *(const bf16x8*)(&As[wm * 64 + foff[mt][h]]);
                bfr[mt][h] = *(const bf16x8*)(&Bs[wn * 64 + foff[mt][h]]);
            }
        for (int mt = 0; mt < 4; ++mt)
            for (int nt = 0; nt < 4; ++nt) {
                acc[mt][nt] = __builtin_amdgcn_mfma_f32_16x16x32_bf16(
                    af[mt][0], bfr[nt][0], acc[mt][nt], 0, 0, 0);
                acc[mt][nt] = __builtin_amdgcn_mfma_f32_16x16x32_bf16(
                    af[mt][1], bfr[nt][1], acc[mt][nt], 0, 0, 0);
            }
        __syncthreads();
    }
    const float c2q = 0.18033688f;            // log2(e)/8 folded into Q
    for (int mt = 0; mt < 4; ++mt) {
        int colv = m0 + wm + mt * 16 + quad * 4;      // 4 consecutive qkv-cols
        float4 bv = *(const float4*)(bias + colv);
        int h = colv / 192;
        int r = colv - h * 192;
        int which = r >> 6;                            // uniform over i (64-aligned)
        int d0 = r & 63;
        for (int nt = 0; nt < 4; ++nt) {
            int tok = n0 + wn + nt * 16 + lc;
            int b = tok >> 12, t = tok & 4095;
            size_t bh = (size_t)(b * NH + h);
            float v0 = acc[mt][nt][0] + bv.x, v1 = acc[mt][nt][1] + bv.y;
            float v2 = acc[mt][nt][2] + bv.z, v3 = acc[mt][nt][3] + bv.w;
            if (which == 0) {
                uint2 u;
                u.x = pack_bf2(v0 * c2q, v1 * c2q);
                u.y = pack_bf2(v2 * c2q, v3 * c2q);
                *(uint2*)(qb + (bh * TT + t) * DK + d0) = u;
            } else if (which == 1) {
                uint2 u;
                u.x = pack_bf2(v0, v1);
                u.y = pack_bf2(v2, v3);
                *(uint2*)(kb + (bh * TT + t) * DK + d0) = u;
            } else {
                unsigned short* vp = vtb + (bh * DK + d0) * TT + t;
                vp[0] = f2bf(v0); vp[TT] = f2bf(v1);
                vp[2 * TT] = f2bf(v2); vp[3 * TT] = f2bf(v3);
            }
        }
    }
}

// ---------------------------------------------------------------------------
// Flash attention tile body, key-sliced: wave w owns keys [w*16, w*16+16) of
// the 64-key tile, ALL 64 q rows (4 subtiles qt). kf read once per tile (2
// ds_read_b128), vf once per dt (4 ds_read_b64) -> 4KB LDS reads/wave-tile.
// 4 independent QK->exp->PV chains per wave (ILP). Row-sum l via ones x P.
// Partial o/l (over this wave's key slice) combine across waves by addition.
// ---------------------------------------------------------------------------
template <bool DIAG>
__device__ __forceinline__ void flash_tile(const unsigned short* __restrict__ Kb,
                                           const unsigned short* __restrict__ Vb,
                                           const bf16x8 (&qf)[4][2],
                                           f32x4 (&o)[4][4], f32x4 (&ol)[4],
                                           int kt, int q0, int w, int quad, int lc) {
    int c0 = quad ^ (lc & 7);
    int sw = lc & 7;
    const bf16x4 ones = {(short)0x3F80, (short)0x3F80, (short)0x3F80, (short)0x3F80};
    bf16x8 kf0 = *(const bf16x8*)(&Kb[(w * 16 + lc) * 64 + c0 * 8]);
    bf16x8 kf1 = *(const bf16x8*)(&Kb[(w * 16 + lc) * 64 + (c0 ^ 4) * 8]);
    bf16x4 pcv[4];
    for (int qt = 0; qt < 4; ++qt) {
        f32x4 s = (f32x4){0.f, 0.f, 0.f, 0.f};
        s = __builtin_amdgcn_mfma_f32_16x16x32_bf16(kf0, qf[qt][0], s, 0, 0, 0);
        s = __builtin_amdgcn_mfma_f32_16x16x32_bf16(kf1, qf[qt][1], s, 0, 0, 0);
        float p[4];
        if (DIAG) {
            int key0 = kt + w * 16 + quad * 4;
            int qcol = q0 + qt * 16 + lc;
            for (int i = 0; i < 4; ++i) {
                float e = __builtin_amdgcn_exp2f(s[i]);
                if (key0 + i > qcol) e = 0.f;
                p[i] = e;
            }
        } else {
            for (int i = 0; i < 4; ++i) p[i] = __builtin_amdgcn_exp2f(s[i]);
        }
        union { uint2 u; bf16x4 v; } pc;
        pc.u.x = pack_bf2(p[0], p[1]);
        pc.u.y = pack_bf2(p[2], p[3]);
        pcv[qt] = pc.v;
        ol[qt] = __builtin_amdgcn_mfma_f32_16x16x16bf16_1k(ones, pcv[qt], ol[qt], 0, 0, 0);
    }
    int c8 = (w * 2 + (quad >> 1)) ^ sw;
    int voff = c8 * 8 + (quad & 1) * 4;
    for (int dt = 0; dt < 4; ++dt) {
        bf16x4 vf = *(const bf16x4*)(&Vb[(dt * 16 + lc) * 64 + voff]);
        for (int qt = 0; qt < 4; ++qt)
            o[qt][dt] = __builtin_amdgcn_mfma_f32_16x16x16bf16_1k(vf, pcv[qt], o[qt][dt], 0, 0, 0);
    }
}

// ---------------------------------------------------------------------------
// Flash attention (causal). 256 thr = 4 waves; block = 64 q rows; wave w owns
// key-slice w of each 64-key tile (all q rows). Grid/schedule identical to
// R7 (1536 blocks, heavy-first). K/V glds double-buffer (waves 0-1 stage K,
// waves 2-3 stage V). After the k-loop: turn-based cross-wave o/l reduction
// in LDS (aliased over the dead K/V buffers; row stride 68 f32 = conflict-
// light), then normalize + store.
// ---------------------------------------------------------------------------
__global__ __launch_bounds__(256)
void flash_attn(const unsigned short* __restrict__ qbuf,
                const unsigned short* __restrict__ kbuf,
                const unsigned short* __restrict__ vtbuf,
                unsigned short* __restrict__ ctx) {
    __shared__ __align__(16) unsigned char smem[32768];
    // layout: K buf0 @0, K buf1 @8192, V buf0 @16384, V buf1 @24576
    // (pointers computed at use-time; no static-initialized pointer arrays)
    float* o_acc = (float*)smem;                    // [64][68] f32 (17408 B)
    float* l_acc = (float*)(smem + 17408);          // [64] f32

    int bh = blockIdx.x;
    int qblk = 63 - (int)blockIdx.y;               // heavy blocks dispatch first
    int tid = threadIdx.x, lane = tid & 63, w = tid >> 6;
    int quad = lane >> 4, lc = lane & 15;
    const size_t base = (size_t)bh * TT * DK;
    const unsigned short* kb = kbuf + base;
    const unsigned short* vb = vtbuf + base;
    int col8 = ((lane & 7) ^ (lane >> 3)) * 8;     // glds swizzled source col
    int klane = (lane >> 3) * DK + col8;
    int vlane = (lane >> 3) * TT + col8;
    size_t hb = (size_t)(bh / NH) * TT * DMODEL + (size_t)(bh % NH) * DK;

    int q0 = qblk * 64;                            // block's 64 q rows
    int ntile = qblk + 1;

    bf16x8 qf[4][2];                               // pre-scaled Q fragments
    for (int qt = 0; qt < 4; ++qt) {
        const unsigned short* qp = qbuf + base + (size_t)(q0 + qt * 16 + lc) * DK;
        qf[qt][0] = *(const bf16x8*)(qp + quad * 8);
        qf[qt][1] = *(const bf16x8*)(qp + 32 + quad * 8);
    }
    f32x4 o[4][4];
    for (int qt = 0; qt < 4; ++qt)
        for (int dt = 0; dt < 4; ++dt) o[qt][dt] = (f32x4){0.f, 0.f, 0.f, 0.f};
    f32x4 ol[4];
    for (int qt = 0; qt < 4; ++qt) ol[qt] = (f32x4){0.f, 0.f, 0.f, 0.f};

    {   // stage tile 0 -> buf 0 (waves 0-1: K rows, waves 2-3: Vt rows)
        int rb = (w & 1) * 4;
        if (w < 2)
            for (int r = 0; r < 4; ++r)
                glds16(kb + (size_t)((rb + r) * 8) * DK + klane,
                       (unsigned short*)(smem) + (rb + r) * 512);
        else
            for (int r = 0; r < 4; ++r)
                glds16(vb + (size_t)((rb + r) * 8) * TT + vlane,
                       (unsigned short*)(smem + 16384) + (rb + r) * 512);
    }
    __syncthreads();

    for (int ti = 0; ti < ntile; ++ti) {
        int cur = ti & 1;
        if (ti + 1 < ntile) {                      // async prefetch -> alt buf
            int kn = (ti + 1) * 64;
            int rb = (w & 1) * 4;
            unsigned short* Kalt = (unsigned short*)(smem + (cur ^ 1) * 8192);
            unsigned short* Valt = (unsigned short*)(smem + 16384 + (cur ^ 1) * 8192);
            if (w < 2)
                for (int r = 0; r < 4; ++r)
                    glds16(kb + (size_t)(kn + (rb + r) * 8) * DK + klane,
                           Kalt + (rb + r) * 512);
            else
                for (int r = 0; r < 4; ++r)
                    glds16(vb + (size_t)((rb + r) * 8) * TT + kn + vlane,
                           Valt + (rb + r) * 512);
        }
        int kt = ti * 64;
        const unsigned short* Kcur = (const unsigned short*)(smem + cur * 8192);
        const unsigned short* Vcur = (const unsigned short*)(smem + 16384 + cur * 8192);
        if (ti == ntile - 1)
            flash_tile<true>(Kcur, Vcur, qf, o, ol, kt, q0, w, quad, lc);
        else
            flash_tile<false>(Kcur, Vcur, qf, o, ol, kt, q0, w, quad, lc);
        __syncthreads();                           // cur consumed; alt staged
    }

    // ---- cross-wave reduction of per-key-slice partials (turn-based) ----
    // K/V buffers are dead (no pending glds: last tile issued no prefetch).
    for (int r = 0; r < 4; ++r) {
        if (w == r) {
            for (int qt = 0; qt < 4; ++qt) {
                int row = qt * 16 + lc;
                float* bp = o_acc + row * 68 + quad * 4;
                if (r == 0) {
                    for (int dt = 0; dt < 4; ++dt)
                        *(f32x4*)(bp + dt * 16) = o[qt][dt];
                    if (quad == 0) l_acc[row] = ol[qt][0];
                } else {
                    for (int dt = 0; dt < 4; ++dt) {
                        f32x4 t = *(const f32x4*)(bp + dt * 16);
                        *(f32x4*)(bp + dt * 16) = t + o[qt][dt];
                    }
                    if (quad == 0) l_acc[row] += ol[qt][0];
                }
            }
        }
        __syncthreads();
    }

    // epilogue: wave w handles q rows [w*16, w*16+16); normalize, store
    {
        int row = w * 16 + lc;
        float inv = 1.f / l_acc[row];
        int t = q0 + row;
        unsigned short* cp = ctx + hb + (size_t)t * DMODEL;
        for (int dt = 0; dt < 4; ++dt) {
            f32x4 ov = *(const f32x4*)(o_acc + row * 68 + dt * 16 + quad * 4);
            uint2 u;
            u.x = pack_bf2(ov[0] * inv, ov[1] * inv);
            u.y = pack_bf2(ov[2] * inv, ov[3] * inv);
            *(uint2*)(cp + dt * 16 + quad * 4) = u;
        }
    }
}

// ---------------------------------------------------------------------------
// Out GEMM computing C^T, 64 out-cols x 128 tokens per block (768 blocks).
// A = Wout_t (64 rows), B = ctx (128 rows); unified LDS, glds staging.
// launch_bounds(256,4): 4 blocks/CU.
// ---------------------------------------------------------------------------
__global__ __launch_bounds__(256, 4)
void gemm_out(const unsigned short* __restrict__ Amat, const unsigned short* __restrict__ Bmat,
              const float* __restrict__ bias, float* __restrict__ out) {
    __shared__ unsigned short S[(64 + 128) * 64];   // A then B, 24 KB
    const int K = DMODEL;
    int m0 = blockIdx.y * 64, n0 = blockIdx.x * 128;   // m: out-col, n: token
    int tid = threadIdx.x, lane = tid & 63, w = tid >> 6;
    int wm = (w & 1) * 32, wn = (w >> 1) * 64;
    int quad = lane >> 4, lc = lane & 15;

    const unsigned short* gp[6]; unsigned short* lp[6];
    for (int p = 0; p < 6; ++p) {
        int c = (w * 6 + p) * 64 + lane;      // 16B chunk id (A:0..511, B:512..1535)
        if (c < 512) {
            int row = c >> 3, gc = (c & 7) ^ (row & 7);
            gp[p] = Amat + (size_t)(m0 + row) * K + gc * 8;
        } else {
            int cb = c - 512;
            int row = cb >> 3, gc = (cb & 7) ^ (row & 7);
            gp[p] = Bmat + (size_t)(n0 + row) * K + gc * 8;
        }
        lp[p] = &S[(w * 6 + p) * 512];
    }
    int foffA[2][2], foffB[4][2];
    for (int mt = 0; mt < 2; ++mt)
        for (int h = 0; h < 2; ++h)
            foffA[mt][h] = (wm + mt * 16 + lc) * 64 + (((quad + 4 * h) ^ (lc & 7)) * 8);
    for (int nt = 0; nt < 4; ++nt)
        for (int h = 0; h < 2; ++h)
            foffB[nt][h] = 4096 + (wn + nt * 16 + lc) * 64 + (((quad + 4 * h) ^ (lc & 7)) * 8);

    f32x4 acc[2][4];
    for (int a = 0; a < 2; ++a)
        for (int b2 = 0; b2 < 4; ++b2) acc[a][b2] = (f32x4){0.f, 0.f, 0.f, 0.f};

    for (int k0 = 0; k0 < K; k0 += 64) {
        for (int p = 0; p < 6; ++p) glds16(gp[p] + k0, lp[p]);
        __syncthreads();
        bf16x8 af[2][2], bfr[4][2];
        for (int mt = 0; mt < 2; ++mt)
            for (int h = 0; h < 2; ++h) af[mt][h] = *(const bf16x8*)(&S[foffA[mt][h]]);
        for (int nt = 0; nt < 4; ++nt)
            for (int h = 0; h < 2; ++h) bfr[nt][h] = *(const bf16x8*)(&S[foffB[nt][h]]);
        for (int mt = 0; mt < 2; ++mt)
            for (int nt = 0; nt < 4; ++nt) {
                acc[mt][nt] = __builtin_amdgcn_mfma_f32_16x16x32_bf16(
                    af[mt][0], bfr[nt][0], acc[mt][nt], 0, 0, 0);
                acc[mt][nt] = __builtin_amdgcn_mfma_f32_16x16x32_bf16(
                    af[mt][1], bfr[nt][1], acc[mt][nt], 0, 0, 0);
            }
        __syncthreads();
    }
    for (int mt = 0; mt < 2; ++mt) {
        int colv = m0 + wm + mt * 16 + quad * 4;
        float4 bv = *(const float4*)(bias + colv);
        for (int nt = 0; nt < 4; ++nt) {
            int tok = n0 + wn + nt * 16 + lc;
            float4 ov;
            ov.x = acc[mt][nt][0] + bv.x;
            ov.y = acc[mt][nt][1] + bv.y;
            ov.z = acc[mt][nt][2] + bv.z;
            ov.w = acc[mt][nt][3] + bv.w;
            *(float4*)(out + (size_t)tok * DMODEL + colv) = ov;
        }
    }
}

// ---------------------------------------------------------------------------
extern "C" void kernel_launch(void* const* d_in, const int* in_sizes, int n_in,
                              void* d_out, int out_size, void* d_ws, size_t ws_size,
                              hipStream_t stream) {
    const float* x     = (const float*)d_in[0];
    // d_in[1] = mask (hard-coded causal; unused)
    const float* W_qkv = (const float*)d_in[2];
    const float* b_qkv = (const float*)d_in[3];
    const float* W_out = (const float*)d_in[4];
    const float* b_out = (const float*)d_in[5];
    float* out = (float*)d_out;

    unsigned short* ws = (unsigned short*)d_ws;
    unsigned short* Wqkv_t = ws;                                    // 2304*768
    unsigned short* Wout_t = Wqkv_t + (size_t)NQKV * DMODEL;        // 768*768
    unsigned short* q_buf  = Wout_t + (size_t)DMODEL * DMODEL;      // 24*4096*64
    unsigned short* k_buf  = q_buf  + (size_t)2 * NH * TT * DK;
    unsigned short* vt_buf = k_buf  + (size_t)2 * NH * TT * DK;
    unsigned short* ctx    = vt_buf + (size_t)2 * NH * TT * DK;     // 2*4096*768
    unsigned short* x_bf   = ctx;   // alias: dead before flash writes ctx

    prep<<<dim3(6720), 256, 0, stream>>>(x, x_bf, W_qkv, Wqkv_t, W_out, Wout_t);
    gemm_qkv<<<dim3((2 * TT) / 128, NQKV / 128), 256, 0, stream>>>(
        Wqkv_t, x_bf, b_qkv, q_buf, k_buf, vt_buf);
    flash_attn<<<dim3(2 * NH, TT / 64), 256, 0, stream>>>(q_buf, k_buf, vt_buf, ctx);
    gemm_out<<<dim3((2 * TT) / 128, DMODEL / 64), 256, 0, stream>>>(
        Wout_t, ctx, b_out, out);
}

// Round 5
// 275.607 us; speedup vs baseline: 1.0936x; 1.0120x over previous
//
#include <hip/hip_runtime.h>
#include <hip/hip_bf16.h>
#include <stdint.h>

// ---------------------------------------------------------------------------
// Causal MHA, B=2 T=4096 D=768 H=12 dk=64, bf16 MFMA path.
// R12: R7..R11 established flash is latency/occupancy-bound: dur tracks
// resident waves monotonically (R7 20 w/CU = 91us best; every restructure
// that cut LDS traffic but lost waves regressed). Keep R7's per-wave shape
// EXACTLY (16 q-rows/wave, VGPR~52) but halve the K/V tile to 32 keys:
// LDS 32KB->16KB => 8 blocks/CU = 32 waves/CU (hw cap), all 1536 blocks
// co-resident. launch_bounds(256,8) pins VGPR<=64. V swizzle re-derived for
// 64B rows (XOR chunk with (row>>1)&3, 2-way/free). Heavy+light y-pairing
// for per-CU balance (all-resident => pairing is pure balance, no queueing).
// ---------------------------------------------------------------------------

typedef __attribute__((ext_vector_type(8))) short bf16x8;   // 8 bf16 = 4 VGPRs
typedef __attribute__((ext_vector_type(4))) short bf16x4;   // 4 bf16 = 2 VGPRs
typedef __attribute__((ext_vector_type(4))) float f32x4;

#define TT 4096
#define NH 12
#define DK 64
#define DMODEL 768
#define NQKV 2304

__device__ __forceinline__ unsigned short f2bf(float f) {
    union { float f; unsigned u; } v; v.f = f;
    unsigned u = v.u;
    return (unsigned short)((u + 0x7fffu + ((u >> 16) & 1u)) >> 16);  // RNE
}
__device__ __forceinline__ unsigned fbits(float f) {
    union { float f; unsigned u; } v; v.f = f; return v.u;
}
// pack two fp32 -> two bf16 (round-half-up): lo16=a, hi16=b
__device__ __forceinline__ unsigned pack_bf2(float a, float b) {
    return __builtin_amdgcn_perm(fbits(b) + 0x8000u, fbits(a) + 0x8000u, 0x07060302u);
}
// async global->LDS, 16B/lane; LDS dest = wave-uniform base + lane*16
__device__ __forceinline__ void glds16(const void* g, void* l) {
    __builtin_amdgcn_global_load_lds(
        (const __attribute__((address_space(1))) void*)g,
        (__attribute__((address_space(3))) void*)l, 16, 0, 0);
}

// ---------------------------------------------------------------------------
// prep: x->bf16 (blocks [0,6144)), W_qkv transpose ([6144,6576)),
// W_out transpose ([6576,6720)).
// ---------------------------------------------------------------------------
__global__ __launch_bounds__(256)
void prep(const float* __restrict__ x, unsigned short* __restrict__ xb,
          const float* __restrict__ Wq, unsigned short* __restrict__ Wqt,
          const float* __restrict__ Wo, unsigned short* __restrict__ Wot) {
    int b = blockIdx.x;
    if (b < 6144) {
        int i = (b * 256 + threadIdx.x) * 4;
        float4 v = *(const float4*)(x + i);
        uint2 u;
        u.x = pack_bf2(v.x, v.y);
        u.y = pack_bf2(v.z, v.w);
        *(uint2*)(xb + i) = u;
        return;
    }
    __shared__ unsigned short tile[64][65];
    const float* W; unsigned short* Wt; int K, N, bx, by;
    if (b < 6144 + 432) {
        int bb = b - 6144; bx = bb % 36; by = bb / 36;
        W = Wq; Wt = Wqt; K = DMODEL; N = NQKV;
    } else {
        int bb = b - 6576; bx = bb % 12; by = bb / 12;
        W = Wo; Wt = Wot; K = DMODEL; N = DMODEL;
    }
    int k0 = by * 64, n0 = bx * 64;
    int c = threadIdx.x & 63;
    int r0 = threadIdx.x >> 6;
    for (int p = 0; p < 16; ++p) {
        int r = r0 + p * 4;
        tile[r][c] = f2bf(W[(size_t)(k0 + r) * N + n0 + c]);
    }
    __syncthreads();
    for (int p = 0; p < 16; ++p) {
        int n = r0 + p * 4;
        Wt[(size_t)(n0 + n) * K + k0 + c] = tile[c][n];
    }
}

// ---------------------------------------------------------------------------
// QKV GEMM computing C^T: tile rows = qkv-cols (A = Wqkv_t), cols = tokens
// (B = x_bf). Q (incl. bias) pre-scaled by log2(e)/8.
// launch_bounds(256,3): 3 blocks/CU (m97 operating point).
// ---------------------------------------------------------------------------
__global__ __launch_bounds__(256, 3)
void gemm_qkv(const unsigned short* __restrict__ Amat, const unsigned short* __restrict__ Bmat,
              const float* __restrict__ bias, unsigned short* __restrict__ qb,
              unsigned short* __restrict__ kb, unsigned short* __restrict__ vtb) {
    __shared__ unsigned short As[128 * 64];
    __shared__ unsigned short Bs[128 * 64];
    const int K = DMODEL;
    int m0 = blockIdx.y * 128, n0 = blockIdx.x * 128;   // m: qkv-col, n: token
    int tid = threadIdx.x, lane = tid & 63, w = tid >> 6;
    int wm = (w >> 1) * 64, wn = (w & 1) * 64;
    int quad = lane >> 4, lc = lane & 15;

    const unsigned short* agp[4]; const unsigned short* bgp[4];
    unsigned short* alp[4]; unsigned short* blp[4];
    for (int p = 0; p < 4; ++p) {
        int c = (w * 4 + p) * 64 + lane;      // 16B chunk id in tile
        int row = c >> 3, pc = c & 7;
        int gc = pc ^ (row & 7);              // swizzle inverse
        agp[p] = Amat + (size_t)(m0 + row) * K + gc * 8;
        bgp[p] = Bmat + (size_t)(n0 + row) * K + gc * 8;
        alp[p] = &As[(w * 4 + p) * 512];
        blp[p] = &Bs[(w * 4 + p) * 512];
    }
    int foff[4][2];
    for (int mt = 0; mt < 4; ++mt)
        for (int h = 0; h < 2; ++h)
            foff[mt][h] = (mt * 16 + lc) * 64 + (((quad + 4 * h) ^ (lc & 7)) * 8);

    f32x4 acc[4][4];
    for (int a = 0; a < 4; ++a)
        for (int b2 = 0; b2 < 4; ++b2) acc[a][b2] = (f32x4){0.f, 0.f, 0.f, 0.f};

    for (int k0 = 0; k0 < K; k0 += 64) {
        for (int p = 0; p < 4; ++p) {
            glds16(agp[p] + k0, alp[p]);
            glds16(bgp[p] + k0, blp[p]);
        }
        __syncthreads();
        bf16x8 af[4][2], bfr[4][2];
        for (int mt = 0; mt < 4; ++mt)
            for (int h = 0; h < 2; ++h) {
                af[mt][h]  = *(const bf16x8*)(&As[wm * 64 + foff[mt][h]]);
                bfr[mt][h] = *(const bf16x8*)(&Bs[wn * 64 + foff[mt][h]]);
            }
        for (int mt = 0; mt < 4; ++mt)
            for (int nt = 0; nt < 4; ++nt) {
                acc[mt][nt] = __builtin_amdgcn_mfma_f32_16x16x32_bf16(
                    af[mt][0], bfr[nt][0], acc[mt][nt], 0, 0, 0);
                acc[mt][nt] = __builtin_amdgcn_mfma_f32_16x16x32_bf16(
                    af[mt][1], bfr[nt][1], acc[mt][nt], 0, 0, 0);
            }
        __syncthreads();
    }
    const float c2q = 0.18033688f;            // log2(e)/8 folded into Q
    for (int mt = 0; mt < 4; ++mt) {
        int colv = m0 + wm + mt * 16 + quad * 4;      // 4 consecutive qkv-cols
        float4 bv = *(const float4*)(bias + colv);
        int h = colv / 192;
        int r = colv - h * 192;
        int which = r >> 6;                            // uniform over i (64-aligned)
        int d0 = r & 63;
        for (int nt = 0; nt < 4; ++nt) {
            int tok = n0 + wn + nt * 16 + lc;
            int b = tok >> 12, t = tok & 4095;
            size_t bh = (size_t)(b * NH + h);
            float v0 = acc[mt][nt][0] + bv.x, v1 = acc[mt][nt][1] + bv.y;
            float v2 = acc[mt][nt][2] + bv.z, v3 = acc[mt][nt][3] + bv.w;
            if (which == 0) {
                uint2 u;
                u.x = pack_bf2(v0 * c2q, v1 * c2q);
                u.y = pack_bf2(v2 * c2q, v3 * c2q);
                *(uint2*)(qb + (bh * TT + t) * DK + d0) = u;
            } else if (which == 1) {
                uint2 u;
                u.x = pack_bf2(v0, v1);
                u.y = pack_bf2(v2, v3);
                *(uint2*)(kb + (bh * TT + t) * DK + d0) = u;
            } else {
                unsigned short* vp = vtb + (bh * DK + d0) * TT + t;
                vp[0] = f2bf(v0); vp[TT] = f2bf(v1);
                vp[2 * TT] = f2bf(v2); vp[3 * TT] = f2bf(v3);
            }
        }
    }
}

// ---------------------------------------------------------------------------
// Flash attention tile body, 32-key tile (2 ktiles of 16). Same per-wave
// shape as R7: 16 q rows (qf0,qf1), o[4], ol. K layout [32][64] swizzled as
// R7 ([8-row groups] x XOR chunk with row&7). V layout [64 d][32 keys],
// 64B rows, XOR chunk with (row>>1)&3 -> 2-way (free) read aliasing.
// ---------------------------------------------------------------------------
template <bool DIAG>
__device__ __forceinline__ void flash_tile32(const unsigned short* __restrict__ Kb,
                                             const unsigned short* __restrict__ Vb,
                                             bf16x8 qf0, bf16x8 qf1,
                                             f32x4 (&o)[4], f32x4& ol,
                                             int kt, int q_lo, int quad, int lc) {
    int c0 = quad ^ (lc & 7);
    int fv = (lc >> 1) & 3;                        // V swizzle f(row)
    const bf16x4 ones = {(short)0x3F80, (short)0x3F80, (short)0x3F80, (short)0x3F80};
    for (int ktile = 0; ktile < 2; ++ktile) {
        bf16x8 kf0 = *(const bf16x8*)(&Kb[(ktile * 16 + lc) * 64 + c0 * 8]);
        bf16x8 kf1 = *(const bf16x8*)(&Kb[(ktile * 16 + lc) * 64 + (c0 ^ 4) * 8]);
        f32x4 s = (f32x4){0.f, 0.f, 0.f, 0.f};
        s = __builtin_amdgcn_mfma_f32_16x16x32_bf16(kf0, qf0, s, 0, 0, 0);
        s = __builtin_amdgcn_mfma_f32_16x16x32_bf16(kf1, qf1, s, 0, 0, 0);
        float p[4];
        if (DIAG) {
            int key0 = kt + ktile * 16 + quad * 4;
            int qcol = q_lo + lc;
            for (int i = 0; i < 4; ++i) {
                float e = __builtin_amdgcn_exp2f(s[i]);
                if (key0 + i > qcol) e = 0.f;
                p[i] = e;
            }
        } else {
            for (int i = 0; i < 4; ++i) p[i] = __builtin_amdgcn_exp2f(s[i]);
        }
        union { uint2 u; bf16x4 v; } pc;
        pc.u.x = pack_bf2(p[0], p[1]);
        pc.u.y = pack_bf2(p[2], p[3]);
        ol = __builtin_amdgcn_mfma_f32_16x16x16bf16_1k(ones, pc.v, ol, 0, 0, 0);
        int c_swz = (ktile * 2 + (quad >> 1)) ^ fv;
        int voff = c_swz * 8 + (quad & 1) * 4;
        for (int dt = 0; dt < 4; ++dt) {
            bf16x4 vf = *(const bf16x4*)(&Vb[(dt * 16 + lc) * 32 + voff]);
            o[dt] = __builtin_amdgcn_mfma_f32_16x16x16bf16_1k(vf, pc.v, o[dt], 0, 0, 0);
        }
    }
}

// ---------------------------------------------------------------------------
// Flash attention (causal). 256 thr = 4 waves x 16 q rows (64-row q tile),
// 1536 blocks; 32-key K/V tiles double-buffered => 16KB LDS => 8 blocks/CU
// = 32 waves/CU (hw cap), ALL blocks co-resident. launch_bounds(256,8) pins
// VGPR<=64. Heavy+light y-pairing balances per-CU work. Waves 0-1 stage K,
// waves 2-3 stage V. Per-wave tile classes: full / diag / skip (uniform).
// ---------------------------------------------------------------------------
__global__ __launch_bounds__(256, 8)
void flash_attn(const unsigned short* __restrict__ qbuf,
                const unsigned short* __restrict__ kbuf,
                const unsigned short* __restrict__ vtbuf,
                unsigned short* __restrict__ ctx) {
    __shared__ __align__(16) unsigned char smem[16384];
    // layout: K buf0 @0, K buf1 @4096, V buf0 @8192, V buf1 @12288

    int bh = blockIdx.x;
    int yy = (int)blockIdx.y;                      // 0..63
    int qblk = (yy & 1) ? (yy >> 1) : (63 - (yy >> 1));   // heavy+light pairing
    int tid = threadIdx.x, lane = tid & 63, w = tid >> 6;
    int quad = lane >> 4, lc = lane & 15;
    const size_t base = (size_t)bh * TT * DK;
    const unsigned short* kb = kbuf + base;
    const unsigned short* vb = vtbuf + base;
    int col8 = ((lane & 7) ^ (lane >> 3)) * 8;     // K glds swizzled source col
    int klane = (lane >> 3) * DK + col8;
    int vrow = lane >> 2;                          // V: row within 16-row group
    int vchunk = ((lane & 3) ^ ((lane >> 3) & 3)) * 8;   // V swizzled source col
    size_t hb = (size_t)(bh / NH) * TT * DMODEL + (size_t)(bh % NH) * DK;

    int q_lo = qblk * 64 + w * 16;                 // this wave's 16 q rows
    int ntile = 2 * qblk + 2;                      // 32-key tiles

    bf16x8 qf0, qf1;                               // pre-scaled Q fragment
    {
        const unsigned short* qp = qbuf + base + (size_t)(q_lo + lc) * DK;
        qf0 = *(const bf16x8*)(qp + quad * 8);
        qf1 = *(const bf16x8*)(qp + 32 + quad * 8);
    }
    f32x4 o[4];
    for (int dt = 0; dt < 4; ++dt) o[dt] = (f32x4){0.f, 0.f, 0.f, 0.f};
    f32x4 ol = (f32x4){0.f, 0.f, 0.f, 0.f};       // row-sum accumulator

    {   // stage tile 0 -> buf 0 (waves 0-1: K, waves 2-3: V)
        if (w < 2) {
            for (int r = 0; r < 2; ++r) {
                int g = w * 2 + r;                 // 8-row group of K
                glds16(kb + (size_t)(g * 8) * DK + klane,
                       (unsigned short*)smem + g * 512);
            }
        } else {
            for (int r = 0; r < 2; ++r) {
                int g = (w - 2) * 2 + r;           // 16-row group of V (d rows)
                glds16(vb + (size_t)(g * 16 + vrow) * TT + vchunk,
                       (unsigned short*)(smem + 8192) + g * 512);
            }
        }
    }
    __syncthreads();

    for (int ti = 0; ti < ntile; ++ti) {
        int cur = ti & 1;
        if (ti + 1 < ntile) {                      // async prefetch -> alt buf
            int kn = (ti + 1) * 32;
            if (w < 2) {
                unsigned short* Kalt = (unsigned short*)(smem + (cur ^ 1) * 4096);
                for (int r = 0; r < 2; ++r) {
                    int g = w * 2 + r;
                    glds16(kb + (size_t)(kn + g * 8) * DK + klane, Kalt + g * 512);
                }
            } else {
                unsigned short* Valt = (unsigned short*)(smem + 8192 + (cur ^ 1) * 4096);
                for (int r = 0; r < 2; ++r) {
                    int g = (w - 2) * 2 + r;
                    glds16(vb + (size_t)(g * 16 + vrow) * TT + kn + vchunk, Valt + g * 512);
                }
            }
        }
        int kt = ti * 32;
        if (kt <= q_lo + 15) {                     // not fully masked (wave-uniform)
            const unsigned short* Kcur = (const unsigned short*)(smem + cur * 4096);
            const unsigned short* Vcur = (const unsigned short*)(smem + 8192 + cur * 4096);
            if (kt + 31 > q_lo)
                flash_tile32<true>(Kcur, Vcur, qf0, qf1, o, ol, kt, q_lo, quad, lc);
            else
                flash_tile32<false>(Kcur, Vcur, qf0, qf1, o, ol, kt, q_lo, quad, lc);
        }
        __syncthreads();                           // cur consumed; alt staged
    }

    // epilogue: l_q complete per lane (ones-MFMA); normalize, store
    float inv = 1.f / ol[0];
    int t = q_lo + lc;
    unsigned short* cp = ctx + hb + (size_t)t * DMODEL;
    for (int dt = 0; dt < 4; ++dt) {
        uint2 u;
        u.x = pack_bf2(o[dt][0] * inv, o[dt][1] * inv);
        u.y = pack_bf2(o[dt][2] * inv, o[dt][3] * inv);
        *(uint2*)(cp + dt * 16 + quad * 4) = u;
    }
}

// ---------------------------------------------------------------------------
// Out GEMM computing C^T, 64 out-cols x 128 tokens per block (768 blocks).
// A = Wout_t (64 rows), B = ctx (128 rows); unified LDS, glds staging.
// launch_bounds(256,4): 4 blocks/CU.
// ---------------------------------------------------------------------------
__global__ __launch_bounds__(256, 4)
void gemm_out(const unsigned short* __restrict__ Amat, const unsigned short* __restrict__ Bmat,
              const float* __restrict__ bias, float* __restrict__ out) {
    __shared__ unsigned short S[(64 + 128) * 64];   // A then B, 24 KB
    const int K = DMODEL;
    int m0 = blockIdx.y * 64, n0 = blockIdx.x * 128;   // m: out-col, n: token
    int tid = threadIdx.x, lane = tid & 63, w = tid >> 6;
    int wm = (w & 1) * 32, wn = (w >> 1) * 64;
    int quad = lane >> 4, lc = lane & 15;

    const unsigned short* gp[6]; unsigned short* lp[6];
    for (int p = 0; p < 6; ++p) {
        int c = (w * 6 + p) * 64 + lane;      // 16B chunk id (A:0..511, B:512..1535)
        if (c < 512) {
            int row = c >> 3, gc = (c & 7) ^ (row & 7);
            gp[p] = Amat + (size_t)(m0 + row) * K + gc * 8;
        } else {
            int cb = c - 512;
            int row = cb >> 3, gc = (cb & 7) ^ (row & 7);
            gp[p] = Bmat + (size_t)(n0 + row) * K + gc * 8;
        }
        lp[p] = &S[(w * 6 + p) * 512];
    }
    int foffA[2][2], foffB[4][2];
    for (int mt = 0; mt < 2; ++mt)
        for (int h = 0; h < 2; ++h)
            foffA[mt][h] = (wm + mt * 16 + lc) * 64 + (((quad + 4 * h) ^ (lc & 7)) * 8);
    for (int nt = 0; nt < 4; ++nt)
        for (int h = 0; h < 2; ++h)
            foffB[nt][h] = 4096 + (wn + nt * 16 + lc) * 64 + (((quad + 4 * h) ^ (lc & 7)) * 8);

    f32x4 acc[2][4];
    for (int a = 0; a < 2; ++a)
        for (int b2 = 0; b2 < 4; ++b2) acc[a][b2] = (f32x4){0.f, 0.f, 0.f, 0.f};

    for (int k0 = 0; k0 < K; k0 += 64) {
        for (int p = 0; p < 6; ++p) glds16(gp[p] + k0, lp[p]);
        __syncthreads();
        bf16x8 af[2][2], bfr[4][2];
        for (int mt = 0; mt < 2; ++mt)
            for (int h = 0; h < 2; ++h) af[mt][h] = *(const bf16x8*)(&S[foffA[mt][h]]);
        for (int nt = 0; nt < 4; ++nt)
            for (int h = 0; h < 2; ++h) bfr[nt][h] = *(const bf16x8*)(&S[foffB[nt][h]]);
        for (int mt = 0; mt < 2; ++mt)
            for (int nt = 0; nt < 4; ++nt) {
                acc[mt][nt] = __builtin_amdgcn_mfma_f32_16x16x32_bf16(
                    af[mt][0], bfr[nt][0], acc[mt][nt], 0, 0, 0);
                acc[mt][nt] = __builtin_amdgcn_mfma_f32_16x16x32_bf16(
                    af[mt][1], bfr[nt][1], acc[mt][nt], 0, 0, 0);
            }
        __syncthreads();
    }
    for (int mt = 0; mt < 2; ++mt) {
        int colv = m0 + wm + mt * 16 + quad * 4;
        float4 bv = *(const float4*)(bias + colv);
        for (int nt = 0; nt < 4; ++nt) {
            int tok = n0 + wn + nt * 16 + lc;
            float4 ov;
            ov.x = acc[mt][nt][0] + bv.x;
            ov.y = acc[mt][nt][1] + bv.y;
            ov.z = acc[mt][nt][2] + bv.z;
            ov.w = acc[mt][nt][3] + bv.w;
            *(float4*)(out + (size_t)tok * DMODEL + colv) = ov;
        }
    }
}

// ---------------------------------------------------------------------------
extern "C" void kernel_launch(void* const* d_in, const int* in_sizes, int n_in,
                              void* d_out, int out_size, void* d_ws, size_t ws_size,
                              hipStream_t stream) {
    const float* x     = (const float*)d_in[0];
    // d_in[1] = mask (hard-coded causal; unused)
    const float* W_qkv = (const float*)d_in[2];
    const float* b_qkv = (const float*)d_in[3];
    const float* W_out = (const float*)d_in[4];
    const float* b_out = (const float*)d_in[5];
    float* out = (float*)d_out;

    unsigned short* ws = (unsigned short*)d_ws;
    unsigned short* Wqkv_t = ws;                                    // 2304*768
    unsigned short* Wout_t = Wqkv_t + (size_t)NQKV * DMODEL;        // 768*768
    unsigned short* q_buf  = Wout_t + (size_t)DMODEL * DMODEL;      // 24*4096*64
    unsigned short* k_buf  = q_buf  + (size_t)2 * NH * TT * DK;
    unsigned short* vt_buf = k_buf  + (size_t)2 * NH * TT * DK;
    unsigned short* ctx    = vt_buf + (size_t)2 * NH * TT * DK;     // 2*4096*768
    unsigned short* x_bf   = ctx;   // alias: dead before flash writes ctx

    prep<<<dim3(6720), 256, 0, stream>>>(x, x_bf, W_qkv, Wqkv_t, W_out, Wout_t);
    gemm_qkv<<<dim3((2 * TT) / 128, NQKV / 128), 256, 0, stream>>>(
        Wqkv_t, x_bf, b_qkv, q_buf, k_buf, vt_buf);
    flash_attn<<<dim3(2 * NH, TT / 64), 256, 0, stream>>>(q_buf, k_buf, vt_buf, ctx);
    gemm_out<<<dim3((2 * TT) / 128, DMODEL / 64), 256, 0, stream>>>(
        Wout_t, ctx, b_out, out);
}

// Round 7
// 257.868 us; speedup vs baseline: 1.1689x; 1.0688x over previous
//
#include <hip/hip_runtime.h>
#include <hip/hip_bf16.h>
#include <stdint.h>

// ---------------------------------------------------------------------------
// Causal MHA, B=2 T=4096 D=768 H=12 dk=64, bf16 MFMA path.
// R13 (resubmit; prior run died to container infra, kernel untested):
// flash reverted to R7 exactly (best measured: 91us; R8-R12 proved the
// structure is at a local optimum insensitive to LDS traffic/occupancy/ILP),
// plus T5 s_setprio around MFMA clusters (guide: attn +4-7%, within-probe).
// GEMMs: XCD-rectangle block remap (bijective) so each XCD's L2 holds a
// ~5MB working set (8 B-panels + all A-panels) instead of thrashing 16MB
// across incoherent L2s -> B fetched once per XCD instead of ~18x.
// ---------------------------------------------------------------------------

typedef __attribute__((ext_vector_type(8))) short bf16x8;   // 8 bf16 = 4 VGPRs
typedef __attribute__((ext_vector_type(4))) short bf16x4;   // 4 bf16 = 2 VGPRs
typedef __attribute__((ext_vector_type(4))) float f32x4;

#define TT 4096
#define NH 12
#define DK 64
#define DMODEL 768
#define NQKV 2304

__device__ __forceinline__ unsigned short f2bf(float f) {
    union { float f; unsigned u; } v; v.f = f;
    unsigned u = v.u;
    return (unsigned short)((u + 0x7fffu + ((u >> 16) & 1u)) >> 16);  // RNE
}
__device__ __forceinline__ unsigned fbits(float f) {
    union { float f; unsigned u; } v; v.f = f; return v.u;
}
// pack two fp32 -> two bf16 (round-half-up): lo16=a, hi16=b
__device__ __forceinline__ unsigned pack_bf2(float a, float b) {
    return __builtin_amdgcn_perm(fbits(b) + 0x8000u, fbits(a) + 0x8000u, 0x07060302u);
}
// async global->LDS, 16B/lane; LDS dest = wave-uniform base + lane*16
__device__ __forceinline__ void glds16(const void* g, void* l) {
    __builtin_amdgcn_global_load_lds(
        (const __attribute__((address_space(1))) void*)g,
        (__attribute__((address_space(3))) void*)l, 16, 0, 0);
}

// ---------------------------------------------------------------------------
// prep: x->bf16 (blocks [0,6144)), W_qkv transpose ([6144,6576)),
// W_out transpose ([6576,6720)).
// ---------------------------------------------------------------------------
__global__ __launch_bounds__(256)
void prep(const float* __restrict__ x, unsigned short* __restrict__ xb,
          const float* __restrict__ Wq, unsigned short* __restrict__ Wqt,
          const float* __restrict__ Wo, unsigned short* __restrict__ Wot) {
    int b = blockIdx.x;
    if (b < 6144) {
        int i = (b * 256 + threadIdx.x) * 4;
        float4 v = *(const float4*)(x + i);
        uint2 u;
        u.x = pack_bf2(v.x, v.y);
        u.y = pack_bf2(v.z, v.w);
        *(uint2*)(xb + i) = u;
        return;
    }
    __shared__ unsigned short tile[64][65];
    const float* W; unsigned short* Wt; int K, N, bx, by;
    if (b < 6144 + 432) {
        int bb = b - 6144; bx = bb % 36; by = bb / 36;
        W = Wq; Wt = Wqt; K = DMODEL; N = NQKV;
    } else {
        int bb = b - 6576; bx = bb % 12; by = bb / 12;
        W = Wo; Wt = Wot; K = DMODEL; N = DMODEL;
    }
    int k0 = by * 64, n0 = bx * 64;
    int c = threadIdx.x & 63;
    int r0 = threadIdx.x >> 6;
    for (int p = 0; p < 16; ++p) {
        int r = r0 + p * 4;
        tile[r][c] = f2bf(W[(size_t)(k0 + r) * N + n0 + c]);
    }
    __syncthreads();
    for (int p = 0; p < 16; ++p) {
        int n = r0 + p * 4;
        Wt[(size_t)(n0 + n) * K + k0 + c] = tile[c][n];
    }
}

// ---------------------------------------------------------------------------
// QKV GEMM computing C^T: tile rows = qkv-cols (A = Wqkv_t), cols = tokens
// (B = x_bf). Q (incl. bias) pre-scaled by log2(e)/8.
// launch_bounds(256,3): 3 blocks/CU. XCD-rectangle remap: bid&7 -> XCD,
// each XCD owns n0 in [xcd*8, xcd*8+8) x all 18 m0 -> per-XCD L2 working
// set ~5MB (8 B-panels + 18 A-panels), B fetched once per XCD.
// ---------------------------------------------------------------------------
__global__ __launch_bounds__(256, 3)
void gemm_qkv(const unsigned short* __restrict__ Amat, const unsigned short* __restrict__ Bmat,
              const float* __restrict__ bias, unsigned short* __restrict__ qb,
              unsigned short* __restrict__ kb, unsigned short* __restrict__ vtb) {
    __shared__ unsigned short As[128 * 64];
    __shared__ unsigned short Bs[128 * 64];
    const int K = DMODEL;
    // XCD-rectangle remap (grid 64 x 18 = 1152 blocks, 1152 % 8 == 0)
    int bid = (int)blockIdx.y * 64 + (int)blockIdx.x;
    int idx = bid >> 3;
    int n0 = ((bid & 7) * 8 + (idx & 7)) * 128;         // token tile
    int m0 = (idx >> 3) * 128;                          // qkv-col tile
    int tid = threadIdx.x, lane = tid & 63, w = tid >> 6;
    int wm = (w >> 1) * 64, wn = (w & 1) * 64;
    int quad = lane >> 4, lc = lane & 15;

    const unsigned short* agp[4]; const unsigned short* bgp[4];
    unsigned short* alp[4]; unsigned short* blp[4];
    for (int p = 0; p < 4; ++p) {
        int c = (w * 4 + p) * 64 + lane;      // 16B chunk id in tile
        int row = c >> 3, pc = c & 7;
        int gc = pc ^ (row & 7);              // swizzle inverse
        agp[p] = Amat + (size_t)(m0 + row) * K + gc * 8;
        bgp[p] = Bmat + (size_t)(n0 + row) * K + gc * 8;
        alp[p] = &As[(w * 4 + p) * 512];
        blp[p] = &Bs[(w * 4 + p) * 512];
    }
    int foff[4][2];
    for (int mt = 0; mt < 4; ++mt)
        for (int h = 0; h < 2; ++h)
            foff[mt][h] = (mt * 16 + lc) * 64 + (((quad + 4 * h) ^ (lc & 7)) * 8);

    f32x4 acc[4][4];
    for (int a = 0; a < 4; ++a)
        for (int b2 = 0; b2 < 4; ++b2) acc[a][b2] = (f32x4){0.f, 0.f, 0.f, 0.f};

    for (int k0 = 0; k0 < K; k0 += 64) {
        for (int p = 0; p < 4; ++p) {
            glds16(agp[p] + k0, alp[p]);
            glds16(bgp[p] + k0, blp[p]);
        }
        __syncthreads();
        bf16x8 af[4][2], bfr[4][2];
        for (int mt = 0; mt < 4; ++mt)
            for (int h = 0; h < 2; ++h) {
                af[mt][h]  = *(const bf16x8*)(&As[wm * 64 + foff[mt][h]]);
                bfr[mt][h] = *(const bf16x8*)(&Bs[wn * 64 + foff[mt][h]]);
            }
        for (int mt = 0; mt < 4; ++mt)
            for (int nt = 0; nt < 4; ++nt) {
                acc[mt][nt] = __builtin_amdgcn_mfma_f32_16x16x32_bf16(
                    af[mt][0], bfr[nt][0], acc[mt][nt], 0, 0, 0);
                acc[mt][nt] = __builtin_amdgcn_mfma_f32_16x16x32_bf16(
                    af[mt][1], bfr[nt][1], acc[mt][nt], 0, 0, 0);
            }
        __syncthreads();
    }
    const float c2q = 0.18033688f;            // log2(e)/8 folded into Q
    for (int mt = 0; mt < 4; ++mt) {
        int colv = m0 + wm + mt * 16 + quad * 4;      // 4 consecutive qkv-cols
        float4 bv = *(const float4*)(bias + colv);
        int h = colv / 192;
        int r = colv - h * 192;
        int which = r >> 6;                            // uniform over i (64-aligned)
        int d0 = r & 63;
        for (int nt = 0; nt < 4; ++nt) {
            int tok = n0 + wn + nt * 16 + lc;
            int b = tok >> 12, t = tok & 4095;
            size_t bh = (size_t)(b * NH + h);
            float v0 = acc[mt][nt][0] + bv.x, v1 = acc[mt][nt][1] + bv.y;
            float v2 = acc[mt][nt][2] + bv.z, v3 = acc[mt][nt][3] + bv.w;
            if (which == 0) {
                uint2 u;
                u.x = pack_bf2(v0 * c2q, v1 * c2q);
                u.y = pack_bf2(v2 * c2q, v3 * c2q);
                *(uint2*)(qb + (bh * TT + t) * DK + d0) = u;
            } else if (which == 1) {
                uint2 u;
                u.x = pack_bf2(v0, v1);
                u.y = pack_bf2(v2, v3);
                *(uint2*)(kb + (bh * TT + t) * DK + d0) = u;
            } else {
                unsigned short* vp = vtb + (bh * DK + d0) * TT + t;
                vp[0] = f2bf(v0); vp[TT] = f2bf(v1);
                vp[2 * TT] = f2bf(v2); vp[3 * TT] = f2bf(v3);
            }
        }
    }
}

// ---------------------------------------------------------------------------
// Flash attention tile body (R7 form). DIAG selects causal masking (wave-
// uniform branch at call site). PV interleaved per ktile. Row-sum l via
// ones x P MFMA (5th accumulator). T5: s_setprio(1) around MFMA clusters.
// ---------------------------------------------------------------------------
template <bool DIAG>
__device__ __forceinline__ void flash_tile(const unsigned short* __restrict__ Kb,
                                           const unsigned short* __restrict__ Vb,
                                           bf16x8 qf0, bf16x8 qf1,
                                           f32x4 (&o)[4], f32x4& ol,
                                           int kt, int q_lo, int quad, int lc) {
    int c0 = quad ^ (lc & 7);
    int sw = lc & 7;
    const bf16x4 ones = {(short)0x3F80, (short)0x3F80, (short)0x3F80, (short)0x3F80};
    for (int ktile = 0; ktile < 4; ++ktile) {
        bf16x8 kf0 = *(const bf16x8*)(&Kb[(ktile * 16 + lc) * 64 + c0 * 8]);
        bf16x8 kf1 = *(const bf16x8*)(&Kb[(ktile * 16 + lc) * 64 + (c0 ^ 4) * 8]);
        f32x4 s = (f32x4){0.f, 0.f, 0.f, 0.f};
        __builtin_amdgcn_s_setprio(1);
        s = __builtin_amdgcn_mfma_f32_16x16x32_bf16(kf0, qf0, s, 0, 0, 0);
        s = __builtin_amdgcn_mfma_f32_16x16x32_bf16(kf1, qf1, s, 0, 0, 0);
        __builtin_amdgcn_s_setprio(0);
        float p[4];
        if (DIAG) {
            int key0 = kt + ktile * 16 + quad * 4;
            int qcol = q_lo + lc;
            for (int i = 0; i < 4; ++i) {
                float e = __builtin_amdgcn_exp2f(s[i]);
                if (key0 + i > qcol) e = 0.f;
                p[i] = e;
            }
        } else {
            for (int i = 0; i < 4; ++i) p[i] = __builtin_amdgcn_exp2f(s[i]);
        }
        union { uint2 u; bf16x4 v; } pc;
        pc.u.x = pack_bf2(p[0], p[1]);
        pc.u.y = pack_bf2(p[2], p[3]);
        int c8 = (ktile * 2 + (quad >> 1)) ^ sw;
        int voff = c8 * 8 + (quad & 1) * 4;
        __builtin_amdgcn_s_setprio(1);
        ol = __builtin_amdgcn_mfma_f32_16x16x16bf16_1k(ones, pc.v, ol, 0, 0, 0);
        for (int dt = 0; dt < 4; ++dt) {
            bf16x4 vf = *(const bf16x4*)(&Vb[(dt * 16 + lc) * 64 + voff]);
            o[dt] = __builtin_amdgcn_mfma_f32_16x16x16bf16_1k(vf, pc.v, o[dt], 0, 0, 0);
        }
        __builtin_amdgcn_s_setprio(0);
    }
}

// ---------------------------------------------------------------------------
// Flash attention (causal), R7 form. 256 thr = 4 waves x 16 q rows (64-row
// q tile); heavy-first; K/V glds double-buffer; P in registers; fixed-max
// softmax.
// ---------------------------------------------------------------------------
__global__ __launch_bounds__(256)
void flash_attn(const unsigned short* __restrict__ qbuf,
                const unsigned short* __restrict__ kbuf,
                const unsigned short* __restrict__ vtbuf,
                unsigned short* __restrict__ ctx) {
    __shared__ unsigned short Ks[2][64 * 64];      // [key][d], swizzled
    __shared__ unsigned short Vs[2][64 * 64];      // [d][key], swizzled
    int bh = blockIdx.x;
    int qblk = 63 - (int)blockIdx.y;               // heavy blocks dispatch first
    int tid = threadIdx.x, lane = tid & 63, w = tid >> 6;
    int quad = lane >> 4, lc = lane & 15;
    const size_t base = (size_t)bh * TT * DK;
    const unsigned short* kb = kbuf + base;
    const unsigned short* vb = vtbuf + base;
    int col8 = ((lane & 7) ^ (lane >> 3)) * 8;     // glds swizzled source col
    int klane = (lane >> 3) * DK + col8;
    int vlane = (lane >> 3) * TT + col8;
    size_t hb = (size_t)(bh / NH) * TT * DMODEL + (size_t)(bh % NH) * DK;

    int q_lo = qblk * 64 + w * 16;                 // this wave's 16 q rows
    int ntile = qblk + 1;

    bf16x8 qf0, qf1;                               // pre-scaled Q fragment
    {
        const unsigned short* qp = qbuf + base + (size_t)(q_lo + lc) * DK;
        qf0 = *(const bf16x8*)(qp + quad * 8);
        qf1 = *(const bf16x8*)(qp + 32 + quad * 8);
    }
    f32x4 o[4];
    for (int dt = 0; dt < 4; ++dt) o[dt] = (f32x4){0.f, 0.f, 0.f, 0.f};
    f32x4 ol = (f32x4){0.f, 0.f, 0.f, 0.f};       // row-sum accumulator

    {   // stage tile 0 -> buf 0 (waves 0-1: K rows, waves 2-3: Vt rows)
        int rb = (w & 1) * 4;
        if (w < 2)
            for (int r = 0; r < 4; ++r)
                glds16(kb + (size_t)((rb + r) * 8) * DK + klane, &Ks[0][(rb + r) * 512]);
        else
            for (int r = 0; r < 4; ++r)
                glds16(vb + (size_t)((rb + r) * 8) * TT + vlane, &Vs[0][(rb + r) * 512]);
    }
    __syncthreads();

    for (int ti = 0; ti < ntile; ++ti) {
        int cur = ti & 1;
        if (ti + 1 < ntile) {                      // async prefetch -> alt buf
            int kn = (ti + 1) * 64;
            int rb = (w & 1) * 4;
            if (w < 2)
                for (int r = 0; r < 4; ++r)
                    glds16(kb + (size_t)(kn + (rb + r) * 8) * DK + klane,
                           &Ks[cur ^ 1][(rb + r) * 512]);
            else
                for (int r = 0; r < 4; ++r)
                    glds16(vb + (size_t)((rb + r) * 8) * TT + kn + vlane,
                           &Vs[cur ^ 1][(rb + r) * 512]);
        }
        int kt = ti * 64;
        if (ti == ntile - 1)
            flash_tile<true>(&Ks[cur][0], &Vs[cur][0], qf0, qf1, o, ol,
                             kt, q_lo, quad, lc);
        else
            flash_tile<false>(&Ks[cur][0], &Vs[cur][0], qf0, qf1, o, ol,
                              kt, q_lo, quad, lc);
        __syncthreads();                           // cur consumed; alt staged
    }

    // epilogue: l_q already complete per lane (ones-MFMA); normalize, store
    float inv = 1.f / ol[0];
    int t = q_lo + lc;
    unsigned short* cp = ctx + hb + (size_t)t * DMODEL;
    for (int dt = 0; dt < 4; ++dt) {
        uint2 u;
        u.x = pack_bf2(o[dt][0] * inv, o[dt][1] * inv);
        u.y = pack_bf2(o[dt][2] * inv, o[dt][3] * inv);
        *(uint2*)(cp + dt * 16 + quad * 4) = u;
    }
}

// ---------------------------------------------------------------------------
// Out GEMM computing C^T, 64 out-cols x 128 tokens per block (768 blocks).
// A = Wout_t (64 rows), B = ctx (128 rows); unified LDS, glds staging.
// launch_bounds(256,4): 4 blocks/CU. XCD-rectangle remap as in gemm_qkv.
// ---------------------------------------------------------------------------
__global__ __launch_bounds__(256, 4)
void gemm_out(const unsigned short* __restrict__ Amat, const unsigned short* __restrict__ Bmat,
              const float* __restrict__ bias, float* __restrict__ out) {
    __shared__ unsigned short S[(64 + 128) * 64];   // A then B, 24 KB
    const int K = DMODEL;
    // XCD-rectangle remap (grid 64 x 12 = 768 blocks, 768 % 8 == 0)
    int bid = (int)blockIdx.y * 64 + (int)blockIdx.x;
    int idx = bid >> 3;
    int n0 = ((bid & 7) * 8 + (idx & 7)) * 128;        // token tile
    int m0 = (idx >> 3) * 64;                          // out-col tile
    int tid = threadIdx.x, lane = tid & 63, w = tid >> 6;
    int wm = (w & 1) * 32, wn = (w >> 1) * 64;
    int quad = lane >> 4, lc = lane & 15;

    const unsigned short* gp[6]; unsigned short* lp[6];
    for (int p = 0; p < 6; ++p) {
        int c = (w * 6 + p) * 64 + lane;      // 16B chunk id (A:0..511, B:512..1535)
        if (c < 512) {
            int row = c >> 3, gc = (c & 7) ^ (row & 7);
            gp[p] = Amat + (size_t)(m0 + row) * K + gc * 8;
        } else {
            int cb = c - 512;
            int row = cb >> 3, gc = (cb & 7) ^ (row & 7);
            gp[p] = Bmat + (size_t)(n0 + row) * K + gc * 8;
        }
        lp[p] = &S[(w * 6 + p) * 512];
    }
    int foffA[2][2], foffB[4][2];
    for (int mt = 0; mt < 2; ++mt)
        for (int h = 0; h < 2; ++h)
            foffA[mt][h] = (wm + mt * 16 + lc) * 64 + (((quad + 4 * h) ^ (lc & 7)) * 8);
    for (int nt = 0; nt < 4; ++nt)
        for (int h = 0; h < 2; ++h)
            foffB[nt][h] = 4096 + (wn + nt * 16 + lc) * 64 + (((quad + 4 * h) ^ (lc & 7)) * 8);

    f32x4 acc[2][4];
    for (int a = 0; a < 2; ++a)
        for (int b2 = 0; b2 < 4; ++b2) acc[a][b2] = (f32x4){0.f, 0.f, 0.f, 0.f};

    for (int k0 = 0; k0 < K; k0 += 64) {
        for (int p = 0; p < 6; ++p) glds16(gp[p] + k0, lp[p]);
        __syncthreads();
        bf16x8 af[2][2], bfr[4][2];
        for (int mt = 0; mt < 2; ++mt)
            for (int h = 0; h < 2; ++h) af[mt][h] = *(const bf16x8*)(&S[foffA[mt][h]]);
        for (int nt = 0; nt < 4; ++nt)
            for (int h = 0; h < 2; ++h) bfr[nt][h] = *(const bf16x8*)(&S[foffB[nt][h]]);
        for (int mt = 0; mt < 2; ++mt)
            for (int nt = 0; nt < 4; ++nt) {
                acc[mt][nt] = __builtin_amdgcn_mfma_f32_16x16x32_bf16(
                    af[mt][0], bfr[nt][0], acc[mt][nt], 0, 0, 0);
                acc[mt][nt] = __builtin_amdgcn_mfma_f32_16x16x32_bf16(
                    af[mt][1], bfr[nt][1], acc[mt][nt], 0, 0, 0);
            }
        __syncthreads();
    }
    for (int mt = 0; mt < 2; ++mt) {
        int colv = m0 + wm + mt * 16 + quad * 4;
        float4 bv = *(const float4*)(bias + colv);
        for (int nt = 0; nt < 4; ++nt) {
            int tok = n0 + wn + nt * 16 + lc;
            float4 ov;
            ov.x = acc[mt][nt][0] + bv.x;
            ov.y = acc[mt][nt][1] + bv.y;
            ov.z = acc[mt][nt][2] + bv.z;
            ov.w = acc[mt][nt][3] + bv.w;
            *(float4*)(out + (size_t)tok * DMODEL + colv) = ov;
        }
    }
}

// ---------------------------------------------------------------------------
extern "C" void kernel_launch(void* const* d_in, const int* in_sizes, int n_in,
                              void* d_out, int out_size, void* d_ws, size_t ws_size,
                              hipStream_t stream) {
    const float* x     = (const float*)d_in[0];
    // d_in[1] = mask (hard-coded causal; unused)
    const float* W_qkv = (const float*)d_in[2];
    const float* b_qkv = (const float*)d_in[3];
    const float* W_out = (const float*)d_in[4];
    const float* b_out = (const float*)d_in[5];
    float* out = (float*)d_out;

    unsigned short* ws = (unsigned short*)d_ws;
    unsigned short* Wqkv_t = ws;                                    // 2304*768
    unsigned short* Wout_t = Wqkv_t + (size_t)NQKV * DMODEL;        // 768*768
    unsigned short* q_buf  = Wout_t + (size_t)DMODEL * DMODEL;      // 24*4096*64
    unsigned short* k_buf  = q_buf  + (size_t)2 * NH * TT * DK;
    unsigned short* vt_buf = k_buf  + (size_t)2 * NH * TT * DK;
    unsigned short* ctx    = vt_buf + (size_t)2 * NH * TT * DK;     // 2*4096*768
    unsigned short* x_bf   = ctx;   // alias: dead before flash writes ctx

    prep<<<dim3(6720), 256, 0, stream>>>(x, x_bf, W_qkv, Wqkv_t, W_out, Wout_t);
    gemm_qkv<<<dim3((2 * TT) / 128, NQKV / 128), 256, 0, stream>>>(
        Wqkv_t, x_bf, b_qkv, q_buf, k_buf, vt_buf);
    flash_attn<<<dim3(2 * NH, TT / 64), 256, 0, stream>>>(q_buf, k_buf, vt_buf, ctx);
    gemm_out<<<dim3((2 * TT) / 128, DMODEL / 64), 256, 0, stream>>>(
        Wout_t, ctx, b_out, out);
}